// Round 13
// baseline (55.335 us; speedup 1.0000x reference)
//
#include <hip/hip_runtime.h>

// LLR denoiser, two-phase, atomic-free:
//   Phase 1 (llr_zs): per patch p, S_p = alpha_p * Zhat_p (16x16 ~ THS*G^{-1/2})
//            via register-resident Newton-Schulz; stored bf16 to ws (C-layout).
//            XCD-swizzled, 4 waves/block (fast: ~12.4us).
//   Phase 2 (llr_apply): R3's exact kernel, NO swizzle: per 4x4 cell,
//            W = (sum of covering S_p)/cnt staged in f32 LDS; out = x - W*x,
//            thread = one float4 (cell-width) x 16 channels.
//            A/B decisive test: R3 measured 27us (w/ slow zs); R4 = same code
//            + swizzle = 40.9us. This pairs the unswizzled apply with fast zs.

#define NBATCH  2
#define NCH     16
#define HDIM    512
#define WDIM    512
#define NPH     127
#define NPW     127
#define NPATCH  (NBATCH * NPH * NPW)
#define NCELL   128
#define THS     0.1f
#define NSIT    8

typedef short bf16x8 __attribute__((ext_vector_type(8)));
typedef float f32x4  __attribute__((ext_vector_type(4)));

#define MFMA(a,b,c) __builtin_amdgcn_mfma_f32_16x16x32_bf16((a),(b),(c),0,0,0)

static __device__ inline short f2bf(float x) {
  return __builtin_bit_cast(short, (__bf16)x);   // native RNE convert
}
static __device__ inline float blo2f(unsigned int v) {
  return __builtin_bit_cast(float, v << 16);
}
static __device__ inline float bhi2f(unsigned int v) {
  return __builtin_bit_cast(float, v & 0xffff0000u);
}
static __device__ inline unsigned int pack2bf(float lo, float hi) {
  unsigned int a = (unsigned short)f2bf(lo);
  unsigned int b = (unsigned short)f2bf(hi);
  return (b << 16) | a;
}

// bijective XCD swizzle (m204) — used by llr_zs ONLY
static __device__ inline int xcd_swz(int b, int nwg) {
  const int q = nwg >> 3, r = nwg & 7;
  const int x = b & 7, lo = b >> 3;
  return (x < r ? x * (q + 1) : r * (q + 1) + (x - r) * q) + lo;
}

static __device__ inline bf16x8 fragc(f32x4 v) {
  // symmetric-matrix C-layout -> MFMA A/B fragment (16 nonzero k-slots)
  bf16x8 r;
  r[0] = f2bf(v[0]); r[1] = f2bf(v[1]); r[2] = f2bf(v[2]); r[3] = f2bf(v[3]);
  r[4] = 0; r[5] = 0; r[6] = 0; r[7] = 0;
  return r;
}

// ---------------- Phase 1: per-patch scaled inverse-sqrt matrices ----------
// 256 threads = 4 waves = 4 consecutive patches per block.
#define ZS_NBLK ((NPATCH + 3) / 4)
__global__ __launch_bounds__(256) void llr_zs(const float* __restrict__ x,
                                              uint2* __restrict__ zs) {
  const int blk = xcd_swz(blockIdx.x, ZS_NBLK);
  const int pid = blk * 4 + (threadIdx.x >> 6);  // one wave per patch
  if (pid >= NPATCH) return;
  const int bi  = pid / (NPH * NPW);
  const int pr  = pid % (NPH * NPW);
  const int ph  = pr / NPW, pw = pr % NPW;
  const int h0  = ph * 4, w0 = pw * 4;
  const int l   = threadIdx.x & 63;
  const int j   = l & 15;                      // row/col id in 16x16 tiles
  const int u   = l >> 4;                      // k-group 0..3

  const size_t HW = (size_t)HDIM * WDIM;
  const float* xb = x + (size_t)bi * NCH * HW;

  // load M (16 channels x 64 pixels) in A-frag layout
  const float* pb = xb + (size_t)j * HW + (size_t)h0 * WDIM + w0;
  const int dh0 = (u >> 1), dw0 = 4 * (u & 1);
  float4 q0 = *(const float4*)(pb + (size_t)(dh0 + 0) * WDIM + dw0);
  float4 q1 = *(const float4*)(pb + (size_t)(dh0 + 2) * WDIM + dw0);
  float4 q2 = *(const float4*)(pb + (size_t)(dh0 + 4) * WDIM + dw0);
  float4 q3 = *(const float4*)(pb + (size_t)(dh0 + 6) * WDIM + dw0);

  bf16x8 m0, m1;
  m0[0]=f2bf(q0.x); m0[1]=f2bf(q0.y); m0[2]=f2bf(q0.z); m0[3]=f2bf(q0.w);
  m0[4]=f2bf(q1.x); m0[5]=f2bf(q1.y); m0[6]=f2bf(q1.z); m0[7]=f2bf(q1.w);
  m1[0]=f2bf(q2.x); m1[1]=f2bf(q2.y); m1[2]=f2bf(q2.z); m1[3]=f2bf(q2.w);
  m1[4]=f2bf(q3.x); m1[5]=f2bf(q3.y); m1[6]=f2bf(q3.z); m1[7]=f2bf(q3.w);

  // G = M M^T
  f32x4 g = {0.f, 0.f, 0.f, 0.f};
  g = MFMA(m0, m0, g);
  g = MFMA(m1, m1, g);

  // Frobenius norm^2 of G
  float s2 = g[0]*g[0] + g[1]*g[1] + g[2]*g[2] + g[3]*g[3];
  #pragma unroll
  for (int m = 32; m >= 1; m >>= 1) s2 += __shfl_xor(s2, m, 64);

  uint2 wv = {0u, 0u};
  if (s2 > 1e-20f) {
    const float invf  = rsqrtf(s2);            // 1/f, f = ||G||_F >= lmax
    const float gsc   = 2.0f * invf;           // normalize by t = f/2 (eig in (0,2])
    const float alpha = THS * sqrtf(gsc);      // THS / sqrt(t)

    // coupled Newton-Schulz: Y0 = G/t, Z0 = I; Z -> (G/t)^{-1/2}
    f32x4 Yc, Zc;
    #pragma unroll
    for (int r = 0; r < 4; ++r) {
      Yc[r] = g[r] * gsc;
      Zc[r] = (4 * u + r == j) ? 1.0f : 0.0f;
    }

    const f32x4 zero = {0.f, 0.f, 0.f, 0.f};
    for (int it = 0; it < NSIT - 1; ++it) {
      bf16x8 yF = fragc(Yc), zF = fragc(Zc);
      f32x4 t  = MFMA(zF, yF, zero);           // T = Z*Y
      bf16x8 tF = fragc(t);
      f32x4 py = MFMA(yF, tF, zero);           // Y*T
      f32x4 pz = MFMA(tF, zF, zero);           // T*Z
      #pragma unroll
      for (int r = 0; r < 4; ++r) {
        Yc[r] = 1.5f * Yc[r] - 0.5f * py[r];
        Zc[r] = 1.5f * Zc[r] - 0.5f * pz[r];
      }
    }
    { // final iteration: only Z needed
      bf16x8 yF = fragc(Yc), zF = fragc(Zc);
      f32x4 t  = MFMA(zF, yF, zero);
      bf16x8 tF = fragc(t);
      f32x4 pz = MFMA(tF, zF, zero);
      #pragma unroll
      for (int r = 0; r < 4; ++r) Zc[r] = 1.5f * Zc[r] - 0.5f * pz[r];
    }

    wv.x = pack2bf(alpha * Zc[0], alpha * Zc[1]);
    wv.y = pack2bf(alpha * Zc[2], alpha * Zc[3]);
  }
  zs[(size_t)pid * 64 + l] = wv;               // coalesced 512B per patch
}

// ---------------- Phase 2: R3's apply, verbatim (NO swizzle) ---------------
// Block: one cell-row (4 h) x 128 w (32 cells), 128 threads; thread owns one
// float4 (= one cell width, one row). All global I/O is dwordx4 coalesced.
#define AP_NBLK (NBATCH * (HDIM / 4) * (WDIM / 128))   // 1024
__global__ __launch_bounds__(128) void llr_apply(const float* __restrict__ x,
                                                 const uint2* __restrict__ zs,
                                                 float* __restrict__ out) {
  __shared__ float Wl[32][257];                // [cell][row*16+col], pad vs conflicts

  const int bid = blockIdx.x;                  // bi*512 + ci*4 + wq (NO swizzle)
  const int wq  = bid & 3;
  const int ci  = (bid >> 2) & 127;
  const int bi  = bid >> 9;
  const int t   = threadIdx.x;

  const size_t HW = (size_t)HDIM * WDIM;
  const float* xb = x + (size_t)bi * NCH * HW;
  float* ob = out + (size_t)bi * NCH * HW;

  // ---- stage 1: W[cell] = (sum of covering S_p) / cnt  -> LDS
  const float cnth = 2.0f - (ci == 0) - (ci == NPH);
  {
    const int l  = t & 63;
    const int u  = l >> 4, j = l & 15;
    const int c0 = t >> 6;                     // 0..1
    #pragma unroll
    for (int i = 0; i < 16; ++i) {
      const int cell = i * 2 + c0;             // 0..31
      const int cj   = wq * 32 + cell;         // global cell col 0..127
      float a0 = 0.f, a1 = 0.f, a2 = 0.f, a3 = 0.f;
      #pragma unroll
      for (int a = 0; a < 2; ++a) {
        const int ph = ci - 1 + a;
        if ((unsigned)ph > (unsigned)(NPH - 1)) continue;
        #pragma unroll
        for (int b = 0; b < 2; ++b) {
          const int pw = cj - 1 + b;
          if ((unsigned)pw > (unsigned)(NPW - 1)) continue;
          uint2 z = zs[((size_t)((bi * NPH + ph) * NPW + pw)) * 64 + l];
          a0 += blo2f(z.x); a1 += bhi2f(z.x);
          a2 += blo2f(z.y); a3 += bhi2f(z.y);
        }
      }
      const float cntw = 2.0f - (cj == 0) - (cj == NPW);
      const float s = 1.0f / (cnth * cntw);
      float* wr = &Wl[cell][u * 64 + j];       // rows 4u+r, col j
      wr[0]  = s * a0;
      wr[16] = s * a1;
      wr[32] = s * a2;
      wr[48] = s * a3;
    }
  }
  __syncthreads();

  // ---- stage 2: out = x - W*x, thread = (row r, cell cl), float4 wide
  const int r  = t >> 5;                       // 0..3
  const int cl = t & 31;                       // 0..31
  const int h  = 4 * ci + r;
  const int w0 = wq * 128 + 4 * cl;

  const float* px = xb + (size_t)h * WDIM + w0;
  float4 xv[16];
  #pragma unroll
  for (int e = 0; e < 16; ++e) xv[e] = *(const float4*)(px + e * HW);

  float* po = ob + (size_t)h * WDIM + w0;
  #pragma unroll
  for (int c = 0; c < 16; ++c) {
    float4 d = {0.f, 0.f, 0.f, 0.f};
    #pragma unroll
    for (int e = 0; e < 16; ++e) {
      const float w = Wl[cl][c * 16 + e];      // bank=cell: conflict-free bcast
      d.x += w * xv[e].x; d.y += w * xv[e].y;
      d.z += w * xv[e].z; d.w += w * xv[e].w;
    }
    float4 o;
    o.x = xv[c].x - d.x; o.y = xv[c].y - d.y;
    o.z = xv[c].z - d.z; o.w = xv[c].w - d.w;
    *(float4*)(po + (size_t)c * HW) = o;
  }
}

extern "C" void kernel_launch(void* const* d_in, const int* in_sizes, int n_in,
                              void* d_out, int out_size, void* d_ws, size_t ws_size,
                              hipStream_t stream) {
  const float* x = (const float*)d_in[0];
  float* out = (float*)d_out;
  uint2* zs = (uint2*)d_ws;                    // 32258*512B = 16.5 MB

  llr_zs<<<dim3(ZS_NBLK), dim3(256), 0, stream>>>(x, zs);
  llr_apply<<<dim3(AP_NBLK), dim3(128), 0, stream>>>(x, zs, out);
}

// Round 14
// 48.644 us; speedup vs baseline: 1.1375x; 1.1375x over previous
//
#include <hip/hip_runtime.h>

// LLR denoiser, two-phase, atomic-free:
//   Phase 1 (llr_zs): per patch p, S_p = alpha_p * Zhat_p (16x16 ~ THS*G^{-1/2})
//            via register-resident Newton-Schulz; bf16 to ws. XCD-swizzled.
//   Phase 2 (llr_apply): block = 4 rows x 64 px (16 cells). R14: x-tile is
//            staged via global_load_lds (async DMA queue — bypasses the
//            per-CU VALU-load miss-queue that capped every R2-R13 variant at
//            ~36-43us regardless of occupancy); outputs via nontemporal
//            stores (no cache allocation -> x/zs stay resident).

#define NBATCH  2
#define NCH     16
#define HDIM    512
#define WDIM    512
#define NPH     127
#define NPW     127
#define NPATCH  (NBATCH * NPH * NPW)
#define NCELL   128
#define THS     0.1f
#define NSIT    8

typedef short bf16x8 __attribute__((ext_vector_type(8)));
typedef float f32x4  __attribute__((ext_vector_type(4)));

#define MFMA(a,b,c) __builtin_amdgcn_mfma_f32_16x16x32_bf16((a),(b),(c),0,0,0)

static __device__ inline short f2bf(float x) {
  return __builtin_bit_cast(short, (__bf16)x);   // native RNE convert
}
static __device__ inline float blo2f(unsigned int v) {
  return __builtin_bit_cast(float, v << 16);
}
static __device__ inline float bhi2f(unsigned int v) {
  return __builtin_bit_cast(float, v & 0xffff0000u);
}
static __device__ inline unsigned int pack2bf(float lo, float hi) {
  unsigned int a = (unsigned short)f2bf(lo);
  unsigned int b = (unsigned short)f2bf(hi);
  return (b << 16) | a;
}

// async global->LDS DMA: 16B/lane, LDS dest = base + lane*16 (HW rule)
#define GLDS16(gsrc, ldst)                                                  \
  __builtin_amdgcn_global_load_lds(                                        \
      (__attribute__((address_space(1))) const void*)(gsrc),               \
      (__attribute__((address_space(3))) void*)(ldst), 16, 0, 0)

// bijective XCD swizzle (m204) — used by llr_zs only
static __device__ inline int xcd_swz(int b, int nwg) {
  const int q = nwg >> 3, r = nwg & 7;
  const int x = b & 7, lo = b >> 3;
  return (x < r ? x * (q + 1) : r * (q + 1) + (x - r) * q) + lo;
}

static __device__ inline bf16x8 fragc(f32x4 v) {
  // symmetric-matrix C-layout -> MFMA A/B fragment (16 nonzero k-slots)
  bf16x8 r;
  r[0] = f2bf(v[0]); r[1] = f2bf(v[1]); r[2] = f2bf(v[2]); r[3] = f2bf(v[3]);
  r[4] = 0; r[5] = 0; r[6] = 0; r[7] = 0;
  return r;
}

// ---------------- Phase 1: per-patch scaled inverse-sqrt matrices ----------
// 256 threads = 4 waves = 4 consecutive patches per block.
#define ZS_NBLK ((NPATCH + 3) / 4)
__global__ __launch_bounds__(256) void llr_zs(const float* __restrict__ x,
                                              uint2* __restrict__ zs) {
  const int blk = xcd_swz(blockIdx.x, ZS_NBLK);
  const int pid = blk * 4 + (threadIdx.x >> 6);  // one wave per patch
  if (pid >= NPATCH) return;
  const int bi  = pid / (NPH * NPW);
  const int pr  = pid % (NPH * NPW);
  const int ph  = pr / NPW, pw = pr % NPW;
  const int h0  = ph * 4, w0 = pw * 4;
  const int l   = threadIdx.x & 63;
  const int j   = l & 15;                      // row/col id in 16x16 tiles
  const int u   = l >> 4;                      // k-group 0..3

  const size_t HW = (size_t)HDIM * WDIM;
  const float* xb = x + (size_t)bi * NCH * HW;

  // load M (16 channels x 64 pixels) in A-frag layout
  const float* pb = xb + (size_t)j * HW + (size_t)h0 * WDIM + w0;
  const int dh0 = (u >> 1), dw0 = 4 * (u & 1);
  float4 q0 = *(const float4*)(pb + (size_t)(dh0 + 0) * WDIM + dw0);
  float4 q1 = *(const float4*)(pb + (size_t)(dh0 + 2) * WDIM + dw0);
  float4 q2 = *(const float4*)(pb + (size_t)(dh0 + 4) * WDIM + dw0);
  float4 q3 = *(const float4*)(pb + (size_t)(dh0 + 6) * WDIM + dw0);

  bf16x8 m0, m1;
  m0[0]=f2bf(q0.x); m0[1]=f2bf(q0.y); m0[2]=f2bf(q0.z); m0[3]=f2bf(q0.w);
  m0[4]=f2bf(q1.x); m0[5]=f2bf(q1.y); m0[6]=f2bf(q1.z); m0[7]=f2bf(q1.w);
  m1[0]=f2bf(q2.x); m1[1]=f2bf(q2.y); m1[2]=f2bf(q2.z); m1[3]=f2bf(q2.w);
  m1[4]=f2bf(q3.x); m1[5]=f2bf(q3.y); m1[6]=f2bf(q3.z); m1[7]=f2bf(q3.w);

  // G = M M^T
  f32x4 g = {0.f, 0.f, 0.f, 0.f};
  g = MFMA(m0, m0, g);
  g = MFMA(m1, m1, g);

  // Frobenius norm^2 of G
  float s2 = g[0]*g[0] + g[1]*g[1] + g[2]*g[2] + g[3]*g[3];
  #pragma unroll
  for (int m = 32; m >= 1; m >>= 1) s2 += __shfl_xor(s2, m, 64);

  uint2 wv = {0u, 0u};
  if (s2 > 1e-20f) {
    const float invf  = rsqrtf(s2);            // 1/f, f = ||G||_F >= lmax
    const float gsc   = 2.0f * invf;           // normalize by t = f/2 (eig in (0,2])
    const float alpha = THS * sqrtf(gsc);      // THS / sqrt(t)

    // coupled Newton-Schulz: Y0 = G/t, Z0 = I; Z -> (G/t)^{-1/2}
    f32x4 Yc, Zc;
    #pragma unroll
    for (int r = 0; r < 4; ++r) {
      Yc[r] = g[r] * gsc;
      Zc[r] = (4 * u + r == j) ? 1.0f : 0.0f;
    }

    const f32x4 zero = {0.f, 0.f, 0.f, 0.f};
    for (int it = 0; it < NSIT - 1; ++it) {
      bf16x8 yF = fragc(Yc), zF = fragc(Zc);
      f32x4 t  = MFMA(zF, yF, zero);           // T = Z*Y
      bf16x8 tF = fragc(t);
      f32x4 py = MFMA(yF, tF, zero);           // Y*T
      f32x4 pz = MFMA(tF, zF, zero);           // T*Z
      #pragma unroll
      for (int r = 0; r < 4; ++r) {
        Yc[r] = 1.5f * Yc[r] - 0.5f * py[r];
        Zc[r] = 1.5f * Zc[r] - 0.5f * pz[r];
      }
    }
    { // final iteration: only Z needed
      bf16x8 yF = fragc(Yc), zF = fragc(Zc);
      f32x4 t  = MFMA(zF, yF, zero);
      bf16x8 tF = fragc(t);
      f32x4 pz = MFMA(tF, zF, zero);
      #pragma unroll
      for (int r = 0; r < 4; ++r) Zc[r] = 1.5f * Zc[r] - 0.5f * pz[r];
    }

    wv.x = pack2bf(alpha * Zc[0], alpha * Zc[1]);
    wv.y = pack2bf(alpha * Zc[2], alpha * Zc[3]);
  }
  zs[(size_t)pid * 64 + l] = wv;               // coalesced 512B per patch
}

// ---------------- Phase 2: apply with DMA-staged x --------------------------
// Block = (bi, ci, seg): 4 rows x 64 px = 16 cells. 256 threads, 4 waves.
// Wave r stages row h=4ci+r, all 16 channels, via 4 global_load_lds instrs:
//   instr e0: lane l moves 16B from x[ch = e0+(l>>4)][h][seg*64 + 4*(l&15)]
//   to Xs[(r*16+ch)*64 + 4*(l&15)]  (= base + 16*l bytes, HW-linear rule ok).
// Gather (R12): 17 rowsum slots -> RS LDS. Then per-thread scalar matvec
// from LDS, nontemporal stores.
#define ST_SEG  8
#define ST_NBLK (NBATCH * NCELL * ST_SEG)   // 2048
__global__ __launch_bounds__(256, 6) void llr_apply(const float* __restrict__ x,
                                                    const uint2* __restrict__ zs,
                                                    float* __restrict__ out) {
  __shared__ float Xs[4 * 16 * 64];            // 16 KB: [row][ch][px]
  __shared__ unsigned int RS[17 * 132];        // 8.9 KB rowsums

  const int bid = blockIdx.x;
  const int seg = bid & 7;
  const int ci  = (bid >> 3) & 127;
  const int bi  = bid >> 10;
  const int t   = threadIdx.x;
  const int r   = t >> 6;                      // wave id = pixel row 0..3
  const int l   = t & 63;                      // lane = pixel column

  const size_t HW = (size_t)HDIM * WDIM;
  const float* xb = x + (size_t)bi * NCH * HW;
  float* ob = out + (size_t)bi * NCH * HW;
  const int h   = 4 * ci + r;
  const int wp0 = seg * 64;

  // ---- stage x row via async DMA (4 instrs/wave, 16 ch x 256B each)
  {
    const float* grow = xb + (size_t)h * WDIM + wp0 + 4 * (l & 15);
    #pragma unroll
    for (int e0 = 0; e0 < 16; e0 += 4) {
      const float* g = grow + (size_t)(e0 + (l >> 4)) * HW;
      GLDS16(g, &Xs[(r * 16 + e0) * 64]);
    }
  }

  // ---- gather rowsum slots -> RS (same as R12, passed)
  {
    const int u = l >> 4, j = l & 15;
    const uint2* zb = zs + (size_t)bi * NPH * NPW * 64;
    const bool vh0 = (ci > 0), vh1 = (ci < NPH);
    const int ph0c = vh0 ? ci - 1 : 0;
    const int ph1c = vh1 ? ci : NPH - 1;
    for (int s = r; s < 17; s += 4) {
      const int pw = seg * 16 - 1 + s;
      const bool vw = ((unsigned)pw <= (unsigned)(NPW - 1));
      const int pwc = vw ? pw : 0;
      uint2 z0 = zb[((size_t)ph0c * NPW + pwc) * 64 + l];
      uint2 z1 = zb[((size_t)ph1c * NPW + pwc) * 64 + l];
      if (!(vw && vh0)) { z0.x = 0u; z0.y = 0u; }
      if (!(vw && vh1)) { z1.x = 0u; z1.y = 0u; }
      const float a0 = blo2f(z0.x) + blo2f(z1.x);
      const float a1 = bhi2f(z0.x) + bhi2f(z1.x);
      const float a2 = blo2f(z0.y) + blo2f(z1.y);
      const float a3 = bhi2f(z0.y) + bhi2f(z1.y);
      RS[s * 132 + 32 * u + j]      = pack2bf(a0, a1);  // pair 2u
      RS[s * 132 + 32 * u + 16 + j] = pack2bf(a2, a3);  // pair 2u+1
    }
  }
  __syncthreads();                             // drains DMA (vmcnt) + ds writes

  // ---- pull this pixel's 16 channels from LDS (banks: l%32, 2-way = free)
  float xv[16];
  #pragma unroll
  for (int e = 0; e < 16; ++e) xv[e] = Xs[(r * 16 + e) * 64 + l];

  // ---- matvec: out = x - (rs[cl]+rs[cl+1]) * x / cnt
  const int cl = l >> 2;                       // cell-local 0..15
  const int cj = seg * 16 + cl;                // global cell col 0..127
  const float cnth = 2.0f - (ci == 0) - (ci == NCELL - 1);
  const float cntw = 2.0f - (cj == 0) - (cj == NCELL - 1);
  const float sc = 1.0f / (cnth * cntw);

  float* po = ob + (size_t)h * WDIM + wp0 + l;
  #pragma unroll
  for (int p = 0; p < 8; ++p) {
    float d0 = 0.f, d1 = 0.f;
    #pragma unroll
    for (int k = 0; k < 4; ++k) {
      const uint4 A = *(const uint4*)&RS[cl * 132 + 16 * p + 4 * k];
      const uint4 B = *(const uint4*)&RS[(cl + 1) * 132 + 16 * p + 4 * k];
      const unsigned int aa[4] = {A.x, A.y, A.z, A.w};
      const unsigned int bb[4] = {B.x, B.y, B.z, B.w};
      #pragma unroll
      for (int c = 0; c < 4; ++c) {
        const int e = 4 * k + c;
        const float wlo = blo2f(aa[c]) + blo2f(bb[c]);
        const float whi = bhi2f(aa[c]) + bhi2f(bb[c]);
        d0 += wlo * xv[e];
        d1 += whi * xv[e];
      }
    }
    __builtin_nontemporal_store(xv[2 * p]     - sc * d0, po + (size_t)(2 * p) * HW);
    __builtin_nontemporal_store(xv[2 * p + 1] - sc * d1, po + (size_t)(2 * p + 1) * HW);
  }
}

extern "C" void kernel_launch(void* const* d_in, const int* in_sizes, int n_in,
                              void* d_out, int out_size, void* d_ws, size_t ws_size,
                              hipStream_t stream) {
  const float* x = (const float*)d_in[0];
  float* out = (float*)d_out;
  uint2* zs = (uint2*)d_ws;                    // 32258*512B = 16.5 MB

  llr_zs<<<dim3(ZS_NBLK), dim3(256), 0, stream>>>(x, zs);
  llr_apply<<<dim3(ST_NBLK), dim3(256), 0, stream>>>(x, zs, out);
}

// Round 15
// 47.118 us; speedup vs baseline: 1.1744x; 1.0324x over previous
//
#include <hip/hip_runtime.h>

// LLR denoiser, two-phase, atomic-free:
//   Phase 1 (llr_zs): per patch p, S_p = alpha_p * Zhat_p (16x16 ~ THS*G^{-1/2})
//            via register-resident Newton-Schulz; bf16 to ws. XCD-swizzled.
//   Phase 2 (llr_strip): block = FULL cell-row strip (4 rows x 512 px).
//            R15 theory: the ~36us apply plateau (R2-R14, invariant under
//            occupancy/gather/DMA changes) is DRAM row thrash on the WRITE
//            path — 16 plane-strided streams in 256-512B runs (R2 measured
//            2x write amplification). Fast kernels (zs, cellw, memset) all
//            write linear. This block writes 16 planes x 8KB CONTIGUOUS runs.

#define NBATCH  2
#define NCH     16
#define HDIM    512
#define WDIM    512
#define NPH     127
#define NPW     127
#define NPATCH  (NBATCH * NPH * NPW)
#define NCELL   128
#define THS     0.1f
#define NSIT    8

typedef short bf16x8 __attribute__((ext_vector_type(8)));
typedef float f32x4  __attribute__((ext_vector_type(4)));

#define MFMA(a,b,c) __builtin_amdgcn_mfma_f32_16x16x32_bf16((a),(b),(c),0,0,0)

static __device__ inline short f2bf(float x) {
  return __builtin_bit_cast(short, (__bf16)x);   // native RNE convert
}
static __device__ inline float blo2f(unsigned int v) {
  return __builtin_bit_cast(float, v << 16);
}
static __device__ inline float bhi2f(unsigned int v) {
  return __builtin_bit_cast(float, v & 0xffff0000u);
}
static __device__ inline unsigned int pack2bf(float lo, float hi) {
  unsigned int a = (unsigned short)f2bf(lo);
  unsigned int b = (unsigned short)f2bf(hi);
  return (b << 16) | a;
}

// bijective XCD swizzle (m204) — used by llr_zs only
static __device__ inline int xcd_swz(int b, int nwg) {
  const int q = nwg >> 3, r = nwg & 7;
  const int x = b & 7, lo = b >> 3;
  return (x < r ? x * (q + 1) : r * (q + 1) + (x - r) * q) + lo;
}

static __device__ inline bf16x8 fragc(f32x4 v) {
  // symmetric-matrix C-layout -> MFMA A/B fragment (16 nonzero k-slots)
  bf16x8 r;
  r[0] = f2bf(v[0]); r[1] = f2bf(v[1]); r[2] = f2bf(v[2]); r[3] = f2bf(v[3]);
  r[4] = 0; r[5] = 0; r[6] = 0; r[7] = 0;
  return r;
}

// ---------------- Phase 1: per-patch scaled inverse-sqrt matrices ----------
// 256 threads = 4 waves = 4 consecutive patches per block.
#define ZS_NBLK ((NPATCH + 3) / 4)
__global__ __launch_bounds__(256) void llr_zs(const float* __restrict__ x,
                                              uint2* __restrict__ zs) {
  const int blk = xcd_swz(blockIdx.x, ZS_NBLK);
  const int pid = blk * 4 + (threadIdx.x >> 6);  // one wave per patch
  if (pid >= NPATCH) return;
  const int bi  = pid / (NPH * NPW);
  const int pr  = pid % (NPH * NPW);
  const int ph  = pr / NPW, pw = pr % NPW;
  const int h0  = ph * 4, w0 = pw * 4;
  const int l   = threadIdx.x & 63;
  const int j   = l & 15;                      // row/col id in 16x16 tiles
  const int u   = l >> 4;                      // k-group 0..3

  const size_t HW = (size_t)HDIM * WDIM;
  const float* xb = x + (size_t)bi * NCH * HW;

  // load M (16 channels x 64 pixels) in A-frag layout
  const float* pb = xb + (size_t)j * HW + (size_t)h0 * WDIM + w0;
  const int dh0 = (u >> 1), dw0 = 4 * (u & 1);
  float4 q0 = *(const float4*)(pb + (size_t)(dh0 + 0) * WDIM + dw0);
  float4 q1 = *(const float4*)(pb + (size_t)(dh0 + 2) * WDIM + dw0);
  float4 q2 = *(const float4*)(pb + (size_t)(dh0 + 4) * WDIM + dw0);
  float4 q3 = *(const float4*)(pb + (size_t)(dh0 + 6) * WDIM + dw0);

  bf16x8 m0, m1;
  m0[0]=f2bf(q0.x); m0[1]=f2bf(q0.y); m0[2]=f2bf(q0.z); m0[3]=f2bf(q0.w);
  m0[4]=f2bf(q1.x); m0[5]=f2bf(q1.y); m0[6]=f2bf(q1.z); m0[7]=f2bf(q1.w);
  m1[0]=f2bf(q2.x); m1[1]=f2bf(q2.y); m1[2]=f2bf(q2.z); m1[3]=f2bf(q2.w);
  m1[4]=f2bf(q3.x); m1[5]=f2bf(q3.y); m1[6]=f2bf(q3.z); m1[7]=f2bf(q3.w);

  // G = M M^T
  f32x4 g = {0.f, 0.f, 0.f, 0.f};
  g = MFMA(m0, m0, g);
  g = MFMA(m1, m1, g);

  // Frobenius norm^2 of G
  float s2 = g[0]*g[0] + g[1]*g[1] + g[2]*g[2] + g[3]*g[3];
  #pragma unroll
  for (int m = 32; m >= 1; m >>= 1) s2 += __shfl_xor(s2, m, 64);

  uint2 wv = {0u, 0u};
  if (s2 > 1e-20f) {
    const float invf  = rsqrtf(s2);            // 1/f, f = ||G||_F >= lmax
    const float gsc   = 2.0f * invf;           // normalize by t = f/2 (eig in (0,2])
    const float alpha = THS * sqrtf(gsc);      // THS / sqrt(t)

    // coupled Newton-Schulz: Y0 = G/t, Z0 = I; Z -> (G/t)^{-1/2}
    f32x4 Yc, Zc;
    #pragma unroll
    for (int r = 0; r < 4; ++r) {
      Yc[r] = g[r] * gsc;
      Zc[r] = (4 * u + r == j) ? 1.0f : 0.0f;
    }

    const f32x4 zero = {0.f, 0.f, 0.f, 0.f};
    for (int it = 0; it < NSIT - 1; ++it) {
      bf16x8 yF = fragc(Yc), zF = fragc(Zc);
      f32x4 t  = MFMA(zF, yF, zero);           // T = Z*Y
      bf16x8 tF = fragc(t);
      f32x4 py = MFMA(yF, tF, zero);           // Y*T
      f32x4 pz = MFMA(tF, zF, zero);           // T*Z
      #pragma unroll
      for (int r = 0; r < 4; ++r) {
        Yc[r] = 1.5f * Yc[r] - 0.5f * py[r];
        Zc[r] = 1.5f * Zc[r] - 0.5f * pz[r];
      }
    }
    { // final iteration: only Z needed
      bf16x8 yF = fragc(Yc), zF = fragc(Zc);
      f32x4 t  = MFMA(zF, yF, zero);
      bf16x8 tF = fragc(t);
      f32x4 pz = MFMA(tF, zF, zero);
      #pragma unroll
      for (int r = 0; r < 4; ++r) Zc[r] = 1.5f * Zc[r] - 0.5f * pz[r];
    }

    wv.x = pack2bf(alpha * Zc[0], alpha * Zc[1]);
    wv.y = pack2bf(alpha * Zc[2], alpha * Zc[3]);
  }
  zs[(size_t)pid * 64 + l] = wv;               // coalesced 512B per patch
}

// ---------------- Phase 2: full-strip apply, linear writes -----------------
// Block = (bi, ci): 4 rows x 512 px = 128 cells. 512 threads, 8 waves.
// Gather: 129 rowsum slots s (pw = s-1; s=0/128 zeroed), slot s by wave s%8;
//   RS[s] = maskedZ(ci-1,pw) + maskedZ(ci,pw), bf16-pair packed.
//   Slot layout: dword d2 = 16p + e (pair p = out-ch 2p,2p+1; in-ch e);
//   pitch 132 dwords -> every uint4 read 16B-aligned.
// Compute: thread (r = t>>7, q = t&127) owns float4 at (h = 4ci+r, w = 4q)
//   = exactly cell q. W(q) = RS[q] + RS[q+1]. out = x - W*x/cnt.
// Stores walk channel pairs -> block emits 16 planes x 8KB contiguous runs.
#define ST_NBLK (NBATCH * NCELL)   // 256
__global__ __launch_bounds__(512, 2) void llr_strip(const float* __restrict__ x,
                                                    const uint2* __restrict__ zs,
                                                    float* __restrict__ out) {
  __shared__ unsigned int RS[129 * 132];       // 68.1 KB

  const int bid = blockIdx.x;
  const int ci  = bid & 127;
  const int bi  = bid >> 7;
  const int t   = threadIdx.x;
  const int w8  = t >> 6;                      // wave 0..7
  const int l   = t & 63;

  const size_t HW = (size_t)HDIM * WDIM;
  const float* xb = x + (size_t)bi * NCH * HW;
  float* ob = out + (size_t)bi * NCH * HW;

  // ---- gather: rowsum slots -> LDS (17 rounds per wave, coalesced 512B)
  {
    const int u = l >> 4, j = l & 15;
    const uint2* zb = zs + (size_t)bi * NPH * NPW * 64;
    const bool vh0 = (ci > 0), vh1 = (ci < NPH);
    const int ph0c = vh0 ? ci - 1 : 0;
    const int ph1c = vh1 ? ci : NPH - 1;
    for (int s = w8; s < 129; s += 8) {
      const int pw = s - 1;
      const bool vw = ((unsigned)pw <= (unsigned)(NPW - 2)); // pw in [0,126]
      const int pwc = vw ? pw : 0;
      uint2 z0 = zb[((size_t)ph0c * NPW + pwc) * 64 + l];
      uint2 z1 = zb[((size_t)ph1c * NPW + pwc) * 64 + l];
      if (!(vw && vh0)) { z0.x = 0u; z0.y = 0u; }
      if (!(vw && vh1)) { z1.x = 0u; z1.y = 0u; }
      const float a0 = blo2f(z0.x) + blo2f(z1.x);
      const float a1 = bhi2f(z0.x) + bhi2f(z1.x);
      const float a2 = blo2f(z0.y) + blo2f(z1.y);
      const float a3 = bhi2f(z0.y) + bhi2f(z1.y);
      RS[s * 132 + 32 * u + j]      = pack2bf(a0, a1);  // pair 2u
      RS[s * 132 + 32 * u + 16 + j] = pack2bf(a2, a3);  // pair 2u+1
    }
  }
  __syncthreads();

  // ---- compute: thread (r, q) = cell q, row h
  const int r = t >> 7;                        // 0..3
  const int q = t & 127;                       // cell / float4 column
  const int h = 4 * ci + r;

  const float* px = xb + (size_t)h * WDIM + 4 * q;
  float4 xv[16];
  #pragma unroll
  for (int e = 0; e < 16; ++e) xv[e] = *(const float4*)(px + (size_t)e * HW);

  const float cnth = 2.0f - (ci == 0) - (ci == NCELL - 1);
  const float cntw = 2.0f - (q == 0) - (q == NCELL - 1);
  const float sc = 1.0f / (cnth * cntw);

  float* po = ob + (size_t)h * WDIM + 4 * q;
  #pragma unroll
  for (int p = 0; p < 8; ++p) {
    float4 d0 = {0.f, 0.f, 0.f, 0.f};
    float4 d1 = {0.f, 0.f, 0.f, 0.f};
    #pragma unroll
    for (int k = 0; k < 4; ++k) {
      const uint4 A = *(const uint4*)&RS[q * 132 + 16 * p + 4 * k];
      const uint4 B = *(const uint4*)&RS[(q + 1) * 132 + 16 * p + 4 * k];
      const unsigned int aa[4] = {A.x, A.y, A.z, A.w};
      const unsigned int bb[4] = {B.x, B.y, B.z, B.w};
      #pragma unroll
      for (int c = 0; c < 4; ++c) {
        const int e = 4 * k + c;
        const float wlo = blo2f(aa[c]) + blo2f(bb[c]);
        const float whi = bhi2f(aa[c]) + bhi2f(bb[c]);
        d0.x += wlo * xv[e].x; d0.y += wlo * xv[e].y;
        d0.z += wlo * xv[e].z; d0.w += wlo * xv[e].w;
        d1.x += whi * xv[e].x; d1.y += whi * xv[e].y;
        d1.z += whi * xv[e].z; d1.w += whi * xv[e].w;
      }
    }
    const int c0 = 2 * p, c1 = 2 * p + 1;
    float4 o0, o1;
    o0.x = xv[c0].x - sc * d0.x; o0.y = xv[c0].y - sc * d0.y;
    o0.z = xv[c0].z - sc * d0.z; o0.w = xv[c0].w - sc * d0.w;
    o1.x = xv[c1].x - sc * d1.x; o1.y = xv[c1].y - sc * d1.y;
    o1.z = xv[c1].z - sc * d1.z; o1.w = xv[c1].w - sc * d1.w;
    *(float4*)(po + (size_t)c0 * HW) = o0;     // block-wide: 8KB contiguous
    *(float4*)(po + (size_t)c1 * HW) = o1;     //   run per channel plane
  }
}

extern "C" void kernel_launch(void* const* d_in, const int* in_sizes, int n_in,
                              void* d_out, int out_size, void* d_ws, size_t ws_size,
                              hipStream_t stream) {
  const float* x = (const float*)d_in[0];
  float* out = (float*)d_out;
  uint2* zs = (uint2*)d_ws;                    // 32258*512B = 16.5 MB

  llr_zs<<<dim3(ZS_NBLK), dim3(256), 0, stream>>>(x, zs);
  llr_strip<<<dim3(ST_NBLK), dim3(512), 0, stream>>>(x, zs, out);
}